// Round 6
// baseline (333.564 us; speedup 1.0000x reference)
//
#include <hip/hip_runtime.h>
#include <math.h>
#include <limits.h>

#define TPB   256
#define TILE  1024          // sort: items per block-tile (256 thr x 4 rounds)
#define RNDS  4
#define MAXT  2048
#define TPAD  64            // pad so unconditional reads past e stay in-bounds
#define MAXK  1024
#define MAXW  29            // fast-path span width (W=30 -> w<=29)
#define WIN   256           // greedy: candidates per producer window
#define RSLOT 8             // greedy: ring slots (power of 2)

#define VOL(x) (*(volatile int*)&(x))

// ===========================================================================
// Kernel A: fused key-build + 4-pass LSD radix argsort. Key+payload packed in
// one u64 (key<<32|idx): one scattered 8B store per item per pass; final pass
// scatters only the 4B index.
// ===========================================================================
struct SortSM {
  union {
    unsigned h[4 * 256];
    struct {
      unsigned wcnt[4][256];
      unsigned runCnt[256];
      unsigned baseL[256];
    } pass;
  };
};

__device__ inline void gbar(unsigned* ctr, int idx, unsigned nblk) {
  __syncthreads();
  if (threadIdx.x == 0) {
    __threadfence();
    atomicAdd(&ctr[idx], 1u);
    while (atomicAdd(&ctr[idx], 0u) < nblk) { __builtin_amdgcn_s_sleep(1); }
    __threadfence();
  }
  __syncthreads();
}

__global__ void __launch_bounds__(TPB, 1) sort_kernel(
    const float* __restrict__ scores, const float* __restrict__ mask,
    int N, int nT, unsigned* ctr, unsigned* ghist, unsigned* tileCnt,
    unsigned long long* kvA, unsigned long long* kvB, int* idxOut) {
  __shared__ SortSM s;
  const int tid = threadIdx.x;
  const int lane = tid & 63;
  const int wave = tid >> 6;

  // ---- P0: build packed keys + all 4 histograms in one read ----
  for (int j = tid; j < 1024; j += TPB) s.h[j] = 0;
  __syncthreads();
  {
    const int tile0 = blockIdx.x * TILE;
    for (int r = 0; r < RNDS; ++r) {
      int i = tile0 + r * 256 + tid;
      if (i < N) {
        float kf = scores[i] + logf(mask[i]);          // mask==1 -> +0 exact
        unsigned u = __float_as_uint(kf);
        u = (u & 0x80000000u) ? ~u : (u | 0x80000000u);
        u = ~u;                                        // descending order
        kvA[i] = ((unsigned long long)u << 32) | (unsigned)i;
        atomicAdd(&s.h[(u & 255u)], 1u);
        atomicAdd(&s.h[256 + ((u >> 8) & 255u)], 1u);
        atomicAdd(&s.h[512 + ((u >> 16) & 255u)], 1u);
        atomicAdd(&s.h[768 + (u >> 24)], 1u);
      }
    }
    __syncthreads();
    for (int j = tid; j < 1024; j += TPB)
      if (s.h[j]) atomicAdd(&ghist[j], s.h[j]);
  }
  gbar(ctr, 0, nT);

  // ---- P1: block 0 scans digit bases (4x256 exclusive) ----
  if (blockIdx.x == 0) {
    for (int p = 0; p < 4; ++p) {
      unsigned v = ghist[p * 256 + tid];
      unsigned* A = s.pass.wcnt[0];
      unsigned* B = s.pass.wcnt[1];
      A[tid] = v;
      __syncthreads();
      for (int off = 1; off < 256; off <<= 1) {
        B[tid] = A[tid] + ((tid >= off) ? A[tid - off] : 0u);
        __syncthreads();
        unsigned* t = A; A = B; B = t;
      }
      ghist[p * 256 + tid] = A[tid] - v;
      __syncthreads();
    }
  }
  gbar(ctr, 1, nT);

  // ---- 4 fused rank/scatter radix passes ----
  for (int p = 0; p < 4; ++p) {
    const unsigned long long* src = (p & 1) ? kvB : kvA;
    unsigned long long*       dst = (p & 1) ? kvA : kvB;
    const int shift = 8 * p;
    const int tile0 = blockIdx.x * TILE;

    s.pass.runCnt[tid] = 0;
    unsigned long long mykv[RNDS]; unsigned mypos[RNDS]; bool myval[RNDS];
    #pragma unroll
    for (int r = 0; r < RNDS; ++r) {
      __syncthreads();
      s.pass.wcnt[0][tid] = 0; s.pass.wcnt[1][tid] = 0;
      s.pass.wcnt[2][tid] = 0; s.pass.wcnt[3][tid] = 0;
      __syncthreads();
      int i = tile0 + r * 256 + tid;
      bool v = (i < N);
      unsigned long long kv = v ? src[i] : 0ull;
      unsigned d = ((unsigned)(kv >> 32) >> shift) & 255u;
      unsigned long long mm = __ballot(v);
      #pragma unroll
      for (int b = 0; b < 8; ++b) {
        unsigned long long bb = __ballot((d >> b) & 1u);
        mm &= ((d >> b) & 1u) ? bb : ~bb;
      }
      int rank = (int)__popcll(mm & ((1ull << lane) - 1ull));
      if (v && rank == 0) s.pass.wcnt[wave][d] = (unsigned)__popcll(mm);
      __syncthreads();
      unsigned run0 = s.pass.runCnt[tid];
      unsigned run = 0;
      #pragma unroll
      for (int w2 = 0; w2 < 4; ++w2) {
        unsigned c = s.pass.wcnt[w2][tid];
        s.pass.wcnt[w2][tid] = run0 + run;
        run += c;
      }
      s.pass.runCnt[tid] = run0 + run;
      __syncthreads();
      mykv[r] = kv; myval[r] = v;
      mypos[r] = v ? (s.pass.wcnt[wave][d] + (unsigned)rank) : 0u;
    }
    __syncthreads();
    tileCnt[blockIdx.x * 256 + tid] = s.pass.runCnt[tid];
    gbar(ctr, 2 + 2 * p, nT);

    unsigned baseacc = ghist[p * 256 + tid];
    for (int t = 0; t < blockIdx.x; ++t)
      baseacc += tileCnt[t * 256 + tid];
    s.pass.baseL[tid] = baseacc;
    __syncthreads();
    #pragma unroll
    for (int r = 0; r < RNDS; ++r) {
      if (myval[r]) {
        unsigned d = ((unsigned)(mykv[r] >> 32) >> shift) & 255u;
        unsigned pos = s.pass.baseL[d] + mypos[r];
        if (p < 3) dst[pos] = mykv[r];
        else       idxOut[pos] = (int)(unsigned)mykv[r];
      }
    }
    if (p < 3) gbar(ctr, 3 + 2 * p, nT);
  }
}

// ===========================================================================
// Kernel B: producer-consumer greedy. Waves 1-3 pre-check 256-candidate
// windows speculatively vs live tables (monotone -> racy reads safe, since
// tables only ever contain earlier-in-order acceptances) and push compressed
// survivors into an LDS ring; wave 0 consumes slots strictly in order,
// re-checks when tables advanced, and resolves in-group crossings exactly.
// NO __syncthreads in the hot loop.
// ===========================================================================
__device__ inline bool cross_check(const unsigned* tabP, int cs, int ce) {
  int w = ce - cs;
  bool crossed = false;
  #pragma unroll
  for (int off = 0; off <= MAXW; ++off) {
    unsigned tv = tabP[cs + off];
    crossed |= ((off >= 1) & (off <= w) & ((tv & 0xFFFFu) > (unsigned)(ce + 1)))
             | ((off < w) & ((tv >> 16) < (unsigned)cs));
  }
  for (int off = MAXW + 1; off <= w; ++off) {     // generic fallback (unused)
    unsigned tv = tabP[cs + off];
    crossed |= ((tv & 0xFFFFu) > (unsigned)(ce + 1));
    if (off < w) crossed |= ((tv >> 16) < (unsigned)cs);
  }
  return crossed;
}

__global__ void __launch_bounds__(TPB, 1) greedy_kernel(
    const int2* __restrict__ spans2, const int* __restrict__ spans,
    const float* __restrict__ scores, const int* __restrict__ order,
    const int* __restrict__ tnum_p, const int* __restrict__ keep_p,
    float* __restrict__ out, int N) {
  __shared__ unsigned tabP[MAXT + TPAD];  // hi16 = e2s(enc), lo16 = s2e+1
  __shared__ int2 tab[MAXT + TPAD];       // authoritative: .x=s2e, .y=e2s
  __shared__ unsigned long long acc[MAXK];
  __shared__ unsigned long long ring[RSLOT][WIN];
  __shared__ int slotCnt[RSLOT];          // -1 = empty
  __shared__ int slotVer[RSLOT];          // gAcc snapshot at producer precheck
  __shared__ int lastCons;                // # consumed windows
  __shared__ int gDone;
  __shared__ int gAcc;                    // published acceptance count
  __shared__ int ticket;
  __shared__ int gcntF;

  const int tid = threadIdx.x;
  const int lane = tid & 63;
  const int wave = tid >> 6;
  const int T  = tnum_p[0];
  const int k0 = keep_p[0];
  const int k  = (k0 < MAXK) ? k0 : MAXK;
  const int nW = (N + WIN - 1) / WIN;
  const unsigned long long lower = (1ull << lane) - 1ull;

  for (int t = tid; t < MAXT + TPAD; t += TPB) {
    tab[t] = make_int2(-1, INT_MAX);
    tabP[t] = 0xFFFF0000u;               // s2e+1 = 0, e2s_enc = 0xFFFF
  }
  if (tid < RSLOT) slotCnt[tid] = -1;
  if (tid == 0) { lastCons = 0; gDone = 0; gAcc = 0; ticket = 0; gcntF = 0; }
  __syncthreads();

  if (wave == 0) {
    // ---------------- CONSUMER (wave 0) ----------------
    int cnt = 0;
    for (int w = 0; w < nW && cnt < k; ++w) {
      int sl = w & (RSLOT - 1);
      int ns;
      while ((ns = VOL(slotCnt[sl])) < 0) { __builtin_amdgcn_s_sleep(1); }
      __threadfence_block();
      int sver = VOL(slotVer[sl]);
      for (int g = 0; g < ns && cnt < k; g += 64) {
        int m = ns - g; if (m > 64) m = 64;
        bool act = lane < m;
        unsigned long long pk = act ? ring[sl][g + lane] : 0ull;
        int gs = (int)(pk >> 48);
        int ge = (int)((pk >> 32) & 0xFFFFu);
        int gc = (int)(unsigned)pk;
        bool pre = act;
        if (cnt != sver)                       // tables advanced since precheck
          pre = act && !cross_check(tabP, gs, ge);
        unsigned long long preB = __ballot(pre);
        if (preB == 0ull) continue;
        int np = (int)__popcll(preB);
        unsigned long long accm;
        int cnt0g = cnt;
        if (np == 1) {
          accm = preB;
          cnt += 1;
        } else {
          // crossing matrix over survivor bits only
          unsigned long long C = 0, bits = preB;
          while (bits) {
            int j = __ffsll((long long)bits) - 1;
            bits &= bits - 1;
            unsigned long long pj = ring[sl][g + j];   // LDS broadcast
            int sj = (int)(pj >> 48), ej = (int)((pj >> 32) & 0xFFFFu);
            bool cr = (gs < sj && sj <= ge && ej > ge) ||
                      (sj < gs && gs <= ej && ej < ge);
            if (cr) C |= 1ull << j;
          }
          if (cnt + np <= k) {
            bool easy = pre && ((C & lower & preB) == 0ull);
            accm = __ballot(easy);
            unsigned long long rem = preB & ~accm;
            while (rem) {
              unsigned long long kmask = __ballot((C & accm & lower) != 0ull);
              int j = __ffsll((long long)rem) - 1;
              rem &= rem - 1;
              if (!((kmask >> j) & 1ull)) accm |= 1ull << j;
            }
            cnt += (int)__popcll(accm);
          } else {
            accm = 0ull;
            unsigned long long rem = preB;
            while (rem && cnt < k) {
              unsigned long long kmask = __ballot((C & accm & lower) != 0ull);
              int j = __ffsll((long long)rem) - 1;
              rem &= rem - 1;
              if (!((kmask >> j) & 1ull)) { accm |= 1ull << j; cnt++; }
            }
          }
        }
        bool accme = ((accm >> lane) & 1ull) != 0ull;
        if (accme) {
          int rank = (int)__popcll(accm & lower);
          acc[cnt0g + rank] =
              ((unsigned long long)(unsigned)(gs * T + ge) << 32) | (unsigned)gc;
          atomicMax(&tab[gs].x, ge);
          atomicMin(&tab[ge].y, gs);
        }
        if (accme) {    // same-wave DS in-order: reads see all lanes' atomics
          int2 tv = tab[gs];
          tabP[gs] = ((unsigned)(tv.y > 65535 ? 65535 : tv.y) << 16)
                   | (unsigned)(tv.x + 1);
          int2 tv2 = tab[ge];
          tabP[ge] = ((unsigned)(tv2.y > 65535 ? 65535 : tv2.y) << 16)
                   | (unsigned)(tv2.x + 1);
        }
        if (lane == 0 && accm) { __threadfence_block(); VOL(gAcc) = cnt; }
      }
      if (lane == 0) {
        __threadfence_block();                 // ring reads done before reuse
        VOL(slotCnt[sl]) = -1;
        VOL(lastCons) = w + 1;
      }
    }
    if (lane == 0) { VOL(gcntF) = cnt; __threadfence_block(); VOL(gDone) = 1; }
  } else {
    // ---------------- PRODUCERS (waves 1-3) ----------------
    for (;;) {
      int myw = 0;
      if (lane == 0) myw = atomicAdd(&ticket, 1);
      myw = __shfl(myw, 0);
      if (myw >= nW) break;
      int sl = myw & (RSLOT - 1);
      bool abort = false;
      while (VOL(lastCons) < myw - (RSLOT - 1)) {   // wait slot reusable
        if (VOL(gDone)) { abort = true; break; }
        __builtin_amdgcn_s_sleep(1);
      }
      if (abort || VOL(gDone)) break;
      int sver = VOL(gAcc);
      __threadfence_block();                 // gAcc read before tabP reads
      int c0 = myw * WIN;
      int cand[4], cs4[4], ce4[4];
      #pragma unroll
      for (int r = 0; r < 4; ++r) {
        int i = c0 + r * 64 + lane;
        cand[r] = (i < N) ? order[i] : -1;
      }
      #pragma unroll
      for (int r = 0; r < 4; ++r) {
        cs4[r] = 0; ce4[r] = 0;
        if (cand[r] >= 0) { int2 sp = spans2[cand[r]]; cs4[r] = sp.x; ce4[r] = sp.y; }
      }
      int ns = 0;
      #pragma unroll
      for (int r = 0; r < 4; ++r) {
        bool ok = (cand[r] >= 0) && !cross_check(tabP, cs4[r], ce4[r]);
        unsigned long long bal = __ballot(ok);
        if (ok) {
          int pos = ns + (int)__popcll(bal & lower);
          ring[sl][pos] = ((unsigned long long)(unsigned)cs4[r] << 48)
                        | ((unsigned long long)(unsigned)ce4[r] << 32)
                        | (unsigned)cand[r];
        }
        ns += (int)__popcll(bal);
      }
      if (lane == 0) {
        __threadfence_block();               // ring data before flag
        VOL(slotVer[sl]) = sver;
        VOL(slotCnt[sl]) = ns;               // publish
      }
    }
  }
  __syncthreads();
  int cnt = gcntF;

  // ---- bitonic ascending sort of acc[0..cnt) by (s*T+e, cand) ----
  int M = 2;
  while (M < cnt) M <<= 1;
  for (int j = tid; j < M; j += TPB)
    if (j >= cnt) acc[j] = ~0ull;
  __syncthreads();
  for (int kk = 2; kk <= M; kk <<= 1) {
    for (int jj = kk >> 1; jj > 0; jj >>= 1) {
      for (int i3 = tid; i3 < M; i3 += TPB) {
        int ixj = i3 ^ jj;
        if (ixj > i3) {
          unsigned long long a = acc[i3], b = acc[ixj];
          bool up = ((i3 & kk) == 0);
          if ((a > b) == up) { acc[i3] = b; acc[ixj] = a; }
        }
      }
      __syncthreads();
    }
  }

  // ---- epilogue: scores | idx | spans | valid, all f32 ----
  for (int j = tid; j < k0; j += TPB) {
    if (j < cnt) {
      int cand = (int)(acc[j] & 0xFFFFFFFFu);
      out[j]                  = scores[cand];
      out[k0 + j]             = (float)cand;
      out[2 * k0 + 2 * j]     = (float)spans[2 * cand];
      out[2 * k0 + 2 * j + 1] = (float)spans[2 * cand + 1];
      out[4 * k0 + j]         = 1.0f;
    } else {
      out[j]                  = 0.0f;
      out[k0 + j]             = 0.0f;
      out[2 * k0 + 2 * j]     = 0.0f;
      out[2 * k0 + 2 * j + 1] = 0.0f;
      out[4 * k0 + j]         = 0.0f;
    }
  }
}

extern "C" void kernel_launch(void* const* d_in, const int* in_sizes, int n_in,
                              void* d_out, int out_size, void* d_ws, size_t ws_size,
                              hipStream_t stream) {
  const int*   spans  = (const int*)d_in[0];
  const float* scores = (const float*)d_in[1];
  const float* mask   = (const float*)d_in[2];
  const int*   tnum   = (const int*)d_in[3];
  const int*   keep   = (const int*)d_in[4];
  const int N = in_sizes[1];
  const int nT = (N + TILE - 1) / TILE;   // 60 for N=61440

  // ws: kvA[N] u64 | kvB[N] u64 | ctr[32] | ghist[1024] | tileCnt[nT*256] | idxOut[N]
  char* p = (char*)d_ws;
  unsigned long long* kvA = (unsigned long long*)p;  p += (size_t)N * 8;
  unsigned long long* kvB = (unsigned long long*)p;  p += (size_t)N * 8;
  unsigned* ctr     = (unsigned*)p;                  p += 32 * 4;
  unsigned* ghist   = (unsigned*)p;                  p += 1024 * 4;
  unsigned* tileCnt = (unsigned*)p;                  p += (size_t)nT * 256 * 4;
  int*      idxOut  = (int*)p;
  float*    out     = (float*)d_out;

  hipMemsetAsync(ctr, 0, (32 + 1024) * sizeof(unsigned), stream);

  sort_kernel<<<nT, TPB, 0, stream>>>(scores, mask, N, nT, ctr, ghist,
                                      tileCnt, kvA, kvB, idxOut);
  greedy_kernel<<<1, TPB, 0, stream>>>((const int2*)spans, spans, scores,
                                       idxOut, tnum, keep, out, N);
}